// Round 3
// baseline (83.745 us; speedup 1.0000x reference)
//
#include <hip/hip_runtime.h>
#include <math.h>

#define DIM     128
#define V_ROWS  20000
#define NPAIRS  65536
#define NFLOAT4 (V_ROWS * DIM / 4)   // 640000

constexpr int K1_BLOCKS  = 256;
constexpr int K1_THREADS = 256;
constexpr int K2_BLOCKS  = 512;
constexpr int K2_THREADS = 256;

// ws layout (bytes):
//   [0..7]    accFx   (int64 fixed-point cost accumulator)
//   [8..11]   ticket1 (K1 arrival counter)
//   [12..15]  ticket2 (K2 arrival counter)
//   [16..31]  pad
//   [32..]    S[128] floats, then partial[K1_BLOCKS*128] floats
#define FXSCALE 1099511627776.0   // 2^40

// ---------------- K1: column sum with decoupled last-block reduce ----------
__global__ __launch_bounds__(K1_THREADS) void k1_colsum(
        const float4* __restrict__ emb4,
        float* __restrict__ partial,   // [K1_BLOCKS][DIM]
        float* __restrict__ S,         // [DIM]
        unsigned int* __restrict__ ticket) {
    const int tid = blockIdx.x * K1_THREADS + threadIdx.x;
    float4 a = make_float4(0.f, 0.f, 0.f, 0.f);
    for (int idx = tid; idx < NFLOAT4; idx += K1_BLOCKS * K1_THREADS) {
        const float4 v = emb4[idx];
        a.x += v.x; a.y += v.y; a.z += v.z; a.w += v.w;
    }
    // stride*4 % 128 == 0 -> thread's 4 columns fixed: (t*4)&127.
    // lane l and l^32 share columns -> fold wave to 32 lanes.
    a.x += __shfl_xor(a.x, 32);
    a.y += __shfl_xor(a.y, 32);
    a.z += __shfl_xor(a.z, 32);
    a.w += __shfl_xor(a.w, 32);

    __shared__ float sm[4][DIM];
    const int wid  = threadIdx.x >> 6;
    const int lane = threadIdx.x & 63;
    const int col  = (threadIdx.x * 4) & 127;
    if (lane < 32) {
        sm[wid][col + 0] = a.x;
        sm[wid][col + 1] = a.y;
        sm[wid][col + 2] = a.z;
        sm[wid][col + 3] = a.w;
    }
    __syncthreads();
    if (threadIdx.x < DIM) {
        partial[blockIdx.x * DIM + threadIdx.x] =
            sm[0][threadIdx.x] + sm[1][threadIdx.x] +
            sm[2][threadIdx.x] + sm[3][threadIdx.x];
    }

    // decoupled arrival: last block reduces all partials -> S
    __threadfence();                       // agent-scope release of partial[]
    __shared__ unsigned int tick;
    if (threadIdx.x == 0) tick = atomicAdd(ticket, 1u);
    __syncthreads();
    if (tick == K1_BLOCKS - 1) {
        const int t = threadIdx.x;
        const int c = t & 127;
        const int g = t >> 7;              // 0..1
        float s = 0.f;
        for (int b = g; b < K1_BLOCKS; b += 2) {
            s += __hip_atomic_load(&partial[b * DIM + c],
                                   __ATOMIC_RELAXED, __HIP_MEMORY_SCOPE_AGENT);
        }
        __shared__ float sm2[2][DIM];
        sm2[g][c] = s;
        __syncthreads();
        if (t < DIM) S[t] = sm2[0][t] + sm2[1][t];
        // kernel boundary makes S visible to K2
    }
}

// ---------------- K2: pairs (16 lanes/pair), fixed-point final reduce -------
__global__ __launch_bounds__(K2_THREADS) void k2_pairs(
        const float* __restrict__ emb,
        const int* __restrict__ iv,
        const int* __restrict__ jv,
        const float* __restrict__ S,
        unsigned long long* __restrict__ accFx,
        unsigned int* __restrict__ ticket,
        float* __restrict__ out) {
    const int lane = threadIdx.x & 63;
    const int wid  = threadIdx.x >> 6;
    const int grp  = lane >> 4;            // 4 pairs per wave per iter
    const int c    = lane & 15;            // 16 lanes per pair, 8 cols each
    const int gw   = blockIdx.x * 4 + wid; // 0..2047

    const float4* S4 = reinterpret_cast<const float4*>(S);
    const float4 s0 = S4[c * 2], s1 = S4[c * 2 + 1];

    float acc = 0.f;
    #pragma unroll
    for (int it = 0; it < 8; ++it) {
        const int p = ((it * 2048 + gw) << 2) + grp;   // covers 0..65535 exactly
        const int i = iv[p];
        const int j = jv[p];
        const float4* ei4 = reinterpret_cast<const float4*>(emb + (size_t)i * DIM);
        const float4* ej4 = reinterpret_cast<const float4*>(emb + (size_t)j * DIM);
        const float4 a0 = ei4[c * 2], a1 = ei4[c * 2 + 1];
        const float4 b0 = ej4[c * 2], b1 = ej4[c * 2 + 1];
        float d = a0.x * b0.x + a0.y * b0.y + a0.z * b0.z + a0.w * b0.w
                + a1.x * b1.x + a1.y * b1.y + a1.z * b1.z + a1.w * b1.w;
        float n = a0.x * s0.x + a0.y * s0.y + a0.z * s0.z + a0.w * s0.w
                + a1.x * s1.x + a1.y * s1.y + a1.z * s1.z + a1.w * s1.w;
        #pragma unroll
        for (int off = 8; off > 0; off >>= 1) {
            d += __shfl_xor(d, off);
            n += __shfl_xor(n, off);
        }
        const float cost = -logf(expf(d - n) + 1e-8f);
        if (c == 0) acc += cost;           // one accumulate per pair
    }

    // wave butterfly (non-leader lanes hold 0)
    #pragma unroll
    for (int off = 32; off > 0; off >>= 1) acc += __shfl_xor(acc, off);

    __shared__ float ls[4];
    if (lane == 0) ls[wid] = acc;
    __syncthreads();
    if (threadIdx.x == 0) {
        const double bsum = (double)(ls[0] + ls[1] + ls[2] + ls[3]);
        const long long q = __double2ll_rn(bsum * FXSCALE);
        atomicAdd(accFx, (unsigned long long)q);   // integer: order-independent
        __threadfence();
        const unsigned int t = atomicAdd(ticket, 1u);
        if (t == K2_BLOCKS - 1) {
            const unsigned long long raw =
                __hip_atomic_load(accFx, __ATOMIC_RELAXED, __HIP_MEMORY_SCOPE_AGENT);
            const double tot = (double)(long long)raw * (1.0 / FXSCALE);
            out[0] = (float)(tot / (double)NPAIRS);
        }
    }
}

extern "C" void kernel_launch(void* const* d_in, const int* in_sizes, int n_in,
                              void* d_out, int out_size, void* d_ws, size_t ws_size,
                              hipStream_t stream) {
    const float* emb = (const float*)d_in[0];
    const int*   iv  = (const int*)d_in[1];
    const int*   jv  = (const int*)d_in[2];
    float* out = (float*)d_out;

    unsigned long long* accFx = (unsigned long long*)d_ws;
    unsigned int* ticket1 = (unsigned int*)((char*)d_ws + 8);
    unsigned int* ticket2 = (unsigned int*)((char*)d_ws + 12);
    float* S       = (float*)((char*)d_ws + 32);
    float* partial = S + DIM;

    hipMemsetAsync(d_ws, 0, 32, stream);   // zero accFx + tickets each call

    hipLaunchKernelGGL(k1_colsum, dim3(K1_BLOCKS), dim3(K1_THREADS), 0, stream,
                       (const float4*)emb, partial, S, ticket1);
    hipLaunchKernelGGL(k2_pairs, dim3(K2_BLOCKS), dim3(K2_THREADS), 0, stream,
                       emb, iv, jv, S, accFx, ticket2, out);
}

// Round 4
// 66.860 us; speedup vs baseline: 1.2525x; 1.2525x over previous
//
#include <hip/hip_runtime.h>
#include <math.h>

#define DIM     128
#define V_ROWS  20000
#define NPAIRS  65536
#define NFLOAT4 (V_ROWS * DIM / 4)   // 640000

constexpr int K1_BLOCKS  = 250;      // 250*256 = 64000 threads, 10 loads each
constexpr int K1_THREADS = 256;
constexpr int K1_STRIDE  = K1_BLOCKS * K1_THREADS;   // 64000 float4
constexpr int K2_BLOCKS  = 1024;     // 4096 waves, 4 pairs/wave/iter, 4 iters
constexpr int K2_THREADS = 256;

#define FXSCALE 1099511627776.0      // 2^40

// ws layout (bytes):
//   [0..7]    accFx   (int64 fixed-point cost accumulator)
//   [8..11]   ticket2 (K2 arrival counter)
//   [12..31]  pad
//   [32..]    SFx[128] int64 fixed-point column sums
// memset 2048 bytes covers all of it.

// ---------------- K1: column sum -> fixed-point atomic SFx ----------------
__global__ __launch_bounds__(K1_THREADS) void k1_colsum(
        const float4* __restrict__ emb4,
        unsigned long long* __restrict__ SFx) {
    const int tid = blockIdx.x * K1_THREADS + threadIdx.x;
    // 10 independent loads, fully unrolled -> single vmcnt drain
    float4 v[10];
    #pragma unroll
    for (int k = 0; k < 10; ++k) v[k] = emb4[tid + k * K1_STRIDE];
    float4 a = make_float4(0.f, 0.f, 0.f, 0.f);
    #pragma unroll
    for (int k = 0; k < 10; ++k) {
        a.x += v[k].x; a.y += v[k].y; a.z += v[k].z; a.w += v[k].w;
    }
    // stride*4 % 128 == 0 -> thread's 4 columns fixed: (tid*4)&127.
    // lane l and l^32 share columns -> fold wave to 32 lanes.
    a.x += __shfl_xor(a.x, 32);
    a.y += __shfl_xor(a.y, 32);
    a.z += __shfl_xor(a.z, 32);
    a.w += __shfl_xor(a.w, 32);

    __shared__ float sm[4][DIM];
    const int wid  = threadIdx.x >> 6;
    const int lane = threadIdx.x & 63;
    const int col  = (threadIdx.x * 4) & 127;
    if (lane < 32) {
        sm[wid][col + 0] = a.x;
        sm[wid][col + 1] = a.y;
        sm[wid][col + 2] = a.z;
        sm[wid][col + 3] = a.w;
    }
    __syncthreads();
    if (threadIdx.x < DIM) {
        const float p = sm[0][threadIdx.x] + sm[1][threadIdx.x] +
                        sm[2][threadIdx.x] + sm[3][threadIdx.x];
        const long long q = __double2ll_rn((double)p * FXSCALE);
        atomicAdd(&SFx[threadIdx.x], (unsigned long long)q);  // integer: exact, order-free
    }
}

// ---------------- K2: pairs (16 lanes/pair), fixed-point final reduce ------
__global__ __launch_bounds__(K2_THREADS) void k2_pairs(
        const float* __restrict__ emb,
        const int* __restrict__ iv,
        const int* __restrict__ jv,
        const unsigned long long* __restrict__ SFx,
        unsigned long long* __restrict__ accFx,
        unsigned int* __restrict__ ticket,
        float* __restrict__ out) {
    const int lane = threadIdx.x & 63;
    const int wid  = threadIdx.x >> 6;
    const int grp  = lane >> 4;            // 4 pairs per wave per iter
    const int c    = lane & 15;            // 16 lanes per pair, 8 cols each
    const int gw   = blockIdx.x * 4 + wid; // 0..4095

    // this lane's 8 columns of S, converted from fixed-point (exact same value
    // for every reader -> deterministic)
    float sv[8];
    #pragma unroll
    for (int k = 0; k < 8; ++k) {
        const long long q = (long long)SFx[c * 8 + k];
        sv[k] = (float)((double)q * (1.0 / FXSCALE));
    }

    float acc = 0.f;
    #pragma unroll
    for (int it = 0; it < 4; ++it) {
        const int p = ((it * 4096 + gw) << 2) + grp;   // covers 0..65535 exactly
        const int i = iv[p];
        const int j = jv[p];
        const float4* ei4 = reinterpret_cast<const float4*>(emb + (size_t)i * DIM);
        const float4* ej4 = reinterpret_cast<const float4*>(emb + (size_t)j * DIM);
        const float4 a0 = ei4[c * 2], a1 = ei4[c * 2 + 1];
        const float4 b0 = ej4[c * 2], b1 = ej4[c * 2 + 1];
        float d = a0.x * b0.x + a0.y * b0.y + a0.z * b0.z + a0.w * b0.w
                + a1.x * b1.x + a1.y * b1.y + a1.z * b1.z + a1.w * b1.w;
        float n = a0.x * sv[0] + a0.y * sv[1] + a0.z * sv[2] + a0.w * sv[3]
                + a1.x * sv[4] + a1.y * sv[5] + a1.z * sv[6] + a1.w * sv[7];
        #pragma unroll
        for (int off = 8; off > 0; off >>= 1) {
            d += __shfl_xor(d, off);
            n += __shfl_xor(n, off);
        }
        const float cost = -logf(expf(d - n) + 1e-8f);
        if (c == 0) acc += cost;           // one accumulate per pair
    }

    // wave butterfly (non-leader lanes hold 0)
    #pragma unroll
    for (int off = 32; off > 0; off >>= 1) acc += __shfl_xor(acc, off);

    __shared__ float ls[4];
    if (lane == 0) ls[wid] = acc;
    __syncthreads();
    if (threadIdx.x == 0) {
        const double bsum = (double)(ls[0] + ls[1] + ls[2] + ls[3]);
        const long long q = __double2ll_rn(bsum * FXSCALE);
        atomicAdd(accFx, (unsigned long long)q);   // integer: order-independent
        __threadfence();
        const unsigned int t = atomicAdd(ticket, 1u);
        if (t == K2_BLOCKS - 1) {
            const unsigned long long raw =
                __hip_atomic_load(accFx, __ATOMIC_RELAXED, __HIP_MEMORY_SCOPE_AGENT);
            const double tot = (double)(long long)raw * (1.0 / FXSCALE);
            out[0] = (float)(tot / (double)NPAIRS);
        }
    }
}

extern "C" void kernel_launch(void* const* d_in, const int* in_sizes, int n_in,
                              void* d_out, int out_size, void* d_ws, size_t ws_size,
                              hipStream_t stream) {
    const float* emb = (const float*)d_in[0];
    const int*   iv  = (const int*)d_in[1];
    const int*   jv  = (const int*)d_in[2];
    float* out = (float*)d_out;

    unsigned long long* accFx = (unsigned long long*)d_ws;
    unsigned int* ticket2 = (unsigned int*)((char*)d_ws + 8);
    unsigned long long* SFx = (unsigned long long*)((char*)d_ws + 32);

    hipMemsetAsync(d_ws, 0, 2048, stream);   // zero accFx + ticket + SFx

    hipLaunchKernelGGL(k1_colsum, dim3(K1_BLOCKS), dim3(K1_THREADS), 0, stream,
                       (const float4*)emb, SFx);
    hipLaunchKernelGGL(k2_pairs, dim3(K2_BLOCKS), dim3(K2_THREADS), 0, stream,
                       emb, iv, jv, SFx, accFx, ticket2, out);
}

// Round 5
// 23.477 us; speedup vs baseline: 3.5671x; 2.8479x over previous
//
#include <hip/hip_runtime.h>
#include <math.h>

#define DIM     128
#define V_ROWS  20000
#define NPAIRS  65536
#define NFLOAT4 (V_ROWS * DIM / 4)   // 640000

constexpr int K1_BLOCKS  = 256;
constexpr int K1_THREADS = 256;
constexpr int K1_STRIDE  = K1_BLOCKS * K1_THREADS;   // 65536 float4
constexpr int K3_BLOCKS  = 1024;     // 4096 waves x 16 pairs = 65536
constexpr int K3_THREADS = 256;

// ws layout (floats):
//   partial[K1_BLOCKS*DIM]  (32768)
//   S[DIM]                  (128)
//   blockpart[K3_BLOCKS]    (1024)
// No atomics anywhere; nothing needs zeroing between calls.

// ---------------- K1: per-block column partial sums (plain stores) ---------
__global__ __launch_bounds__(K1_THREADS) void k1_colsum(
        const float4* __restrict__ emb4,
        float* __restrict__ partial) {
    const int tid = blockIdx.x * K1_THREADS + threadIdx.x;
    float4 a = make_float4(0.f, 0.f, 0.f, 0.f);
    #pragma unroll
    for (int k = 0; k < 9; ++k) {               // 9 unconditional loads
        const float4 v = emb4[tid + k * K1_STRIDE];
        a.x += v.x; a.y += v.y; a.z += v.z; a.w += v.w;
    }
    if (tid + 9 * K1_STRIDE < NFLOAT4) {        // predicated tail load
        const float4 v = emb4[tid + 9 * K1_STRIDE];
        a.x += v.x; a.y += v.y; a.z += v.z; a.w += v.w;
    }
    // stride*4 % 128 == 0 -> thread's 4 columns fixed: (tid*4)&127.
    // lane l and l^32 share columns -> fold wave to 32 lanes.
    a.x += __shfl_xor(a.x, 32);
    a.y += __shfl_xor(a.y, 32);
    a.z += __shfl_xor(a.z, 32);
    a.w += __shfl_xor(a.w, 32);

    __shared__ float sm[4][DIM];
    const int wid  = threadIdx.x >> 6;
    const int lane = threadIdx.x & 63;
    const int col  = (threadIdx.x * 4) & 127;
    if (lane < 32) {
        sm[wid][col + 0] = a.x;
        sm[wid][col + 1] = a.y;
        sm[wid][col + 2] = a.z;
        sm[wid][col + 3] = a.w;
    }
    __syncthreads();
    if (threadIdx.x < DIM) {
        partial[blockIdx.x * DIM + threadIdx.x] =
            sm[0][threadIdx.x] + sm[1][threadIdx.x] +
            sm[2][threadIdx.x] + sm[3][threadIdx.x];
    }
}

// ---------------- K2: fold partials -> S[128] (1 block, parallel loads) ----
__global__ __launch_bounds__(1024) void k2_fold(
        const float* __restrict__ partial,
        float* __restrict__ S) {
    const int t   = threadIdx.x;       // 0..1023
    const int col = t & 127;
    const int g   = t >> 7;            // 0..7, each folds 32 of 256 rows
    float s = 0.f;
    #pragma unroll
    for (int k = 0; k < 32; ++k) {     // 32 independent strided loads
        s += partial[(g + k * 8) * DIM + col];
    }
    __shared__ float sm[8][DIM];
    sm[g][col] = s;
    __syncthreads();
    if (t < DIM) {
        float tot = 0.f;
        #pragma unroll
        for (int g2 = 0; g2 < 8; ++g2) tot += sm[g2][t];
        S[t] = tot;
    }
}

// ---------------- K3: pairs, 16 lanes/pair, 16 pairs/wave ILP-batched ------
__global__ __launch_bounds__(K3_THREADS) void k3_pairs(
        const float4* __restrict__ emb4,   // rows as 32 x float4
        const int* __restrict__ iv,
        const int* __restrict__ jv,
        const float* __restrict__ S,
        float* __restrict__ blockpart) {
    const int lane = threadIdx.x & 63;
    const int wid  = threadIdx.x >> 6;
    const int c    = lane & 15;            // 16 lanes per pair, 8 cols each
    const int grp  = lane >> 4;            // 4 pairs in flight per iter
    const int gw   = blockIdx.x * 4 + wid; // 0..4095
    const int base = gw * 16;              // this wave's 16 consecutive pairs

    const float4* S4 = reinterpret_cast<const float4*>(S);
    const float4 s0 = S4[c * 2], s1 = S4[c * 2 + 1];

    // one coalesced idx load for the wave's 16 pairs (lanes 0..31)
    int idxval = 0;
    if (lane < 16)      idxval = iv[base + lane];
    else if (lane < 32) idxval = jv[base + lane - 16];

    // issue ALL 16 row-gathers (4 float4 per lane per it) before reducing
    float4 A0[4], A1[4], B0[4], B1[4];
    #pragma unroll
    for (int it = 0; it < 4; ++it) {
        const int q = it * 4 + grp;
        const int i = __shfl(idxval, q);
        const int j = __shfl(idxval, 16 + q);
        const float4* ei = emb4 + (size_t)i * 32;
        const float4* ej = emb4 + (size_t)j * 32;
        A0[it] = ei[c * 2]; A1[it] = ei[c * 2 + 1];
        B0[it] = ej[c * 2]; B1[it] = ej[c * 2 + 1];
    }

    float acc = 0.f;
    #pragma unroll
    for (int it = 0; it < 4; ++it) {
        float d = A0[it].x * B0[it].x + A0[it].y * B0[it].y
                + A0[it].z * B0[it].z + A0[it].w * B0[it].w
                + A1[it].x * B1[it].x + A1[it].y * B1[it].y
                + A1[it].z * B1[it].z + A1[it].w * B1[it].w;
        float n = A0[it].x * s0.x + A0[it].y * s0.y
                + A0[it].z * s0.z + A0[it].w * s0.w
                + A1[it].x * s1.x + A1[it].y * s1.y
                + A1[it].z * s1.z + A1[it].w * s1.w;
        #pragma unroll
        for (int off = 8; off > 0; off >>= 1) {
            d += __shfl_xor(d, off);
            n += __shfl_xor(n, off);
        }
        const float cost = -logf(expf(d - n) + 1e-8f);
        if (c == 0) acc += cost;           // one accumulate per pair (grp leader)
    }

    // fold the 4 grp-leaders (lanes 0,16,32,48) -> lane 0
    acc += __shfl_xor(acc, 16);
    acc += __shfl_xor(acc, 32);

    __shared__ float ls[4];
    if (lane == 0) ls[wid] = acc;
    __syncthreads();
    if (threadIdx.x == 0)
        blockpart[blockIdx.x] = ls[0] + ls[1] + ls[2] + ls[3];
}

// ---------------- K4: final reduce (1 block, one parallel load round) ------
__global__ __launch_bounds__(1024) void k4_final(
        const float* __restrict__ blockpart,
        float* __restrict__ out) {
    const int t = threadIdx.x;             // 0..1023
    float s = blockpart[t];
    #pragma unroll
    for (int off = 32; off > 0; off >>= 1) s += __shfl_xor(s, off);
    __shared__ float ls[16];
    if ((t & 63) == 0) ls[t >> 6] = s;
    __syncthreads();
    if (t == 0) {
        float tot = 0.f;
        #pragma unroll
        for (int w = 0; w < 16; ++w) tot += ls[w];
        out[0] = tot / (float)NPAIRS;
    }
}

extern "C" void kernel_launch(void* const* d_in, const int* in_sizes, int n_in,
                              void* d_out, int out_size, void* d_ws, size_t ws_size,
                              hipStream_t stream) {
    const float* emb = (const float*)d_in[0];
    const int*   iv  = (const int*)d_in[1];
    const int*   jv  = (const int*)d_in[2];
    float* out = (float*)d_out;

    float* partial   = (float*)d_ws;                 // 256*128
    float* S         = partial + K1_BLOCKS * DIM;    // 128
    float* blockpart = S + DIM;                      // 1024

    hipLaunchKernelGGL(k1_colsum, dim3(K1_BLOCKS), dim3(K1_THREADS), 0, stream,
                       (const float4*)emb, partial);
    hipLaunchKernelGGL(k2_fold, dim3(1), dim3(1024), 0, stream,
                       partial, S);
    hipLaunchKernelGGL(k3_pairs, dim3(K3_BLOCKS), dim3(K3_THREADS), 0, stream,
                       (const float4*)emb, iv, jv, S, blockpart);
    hipLaunchKernelGGL(k4_final, dim3(1), dim3(1024), 0, stream,
                       blockpart, out);
}